// Round 1
// baseline (122.780 us; speedup 1.0000x reference)
//
#include <hip/hip_runtime.h>
#include <math.h>

// Density loss: B=8, N=2048, C=3, K=16 (includes self-distance 0).
// Kernel 1: one wave per point. Stage batch points (2048 x float4) in LDS.
// Each lane computes 32 distances into registers. Threshold t = 16th-smallest
// of the 64 lane-mins (provable upper bound on true 16th-smallest distance).
// Compact candidates <= t (E[count] ~ 18) into LDS scratch, bitonic-sort 64,
// sum lanes 0..15. Exact fallback path if count > 64 (essentially never).
// Kernel 2: single block reduces 2x8x2048 per-point sums -> scalar MSE.

#define NPTS 2048
#define KSEL 16
#define WAVES_PER_BLOCK 16
#define BLOCK (WAVES_PER_BLOCK * 64)

__device__ __forceinline__ float bitonic64_asc(float v, int lane) {
  // Full ascending bitonic sort of 64 values (one per lane).
  #pragma unroll
  for (int k = 2; k <= 64; k <<= 1) {
    #pragma unroll
    for (int j = k >> 1; j > 0; j >>= 1) {
      float p = __shfl_xor(v, j);
      bool descBlock = (lane & k) != 0;
      bool isLower = (lane & j) == 0;
      v = (isLower != descBlock) ? fminf(v, p) : fmaxf(v, p);
    }
  }
  return v;
}

__global__ __launch_bounds__(BLOCK) void knn_sum16_kernel(
    const float* __restrict__ seed, const float* __restrict__ gt,
    float* __restrict__ out_sums) {
  __shared__ float4 pts[NPTS];                    // 32 KB
  __shared__ float scratch[WAVES_PER_BLOCK][64];  // 4 KB

  const int bid = blockIdx.x;        // 2*8*128 = 2048 blocks
  const int t = bid >> 10;           // tensor: 0=seed 1=gt
  const int b = (bid >> 7) & 7;      // batch
  const int g = bid & 127;           // point-group within batch
  const float* base = (t == 0 ? seed : gt) + b * NPTS * 3;

  const int tid = threadIdx.x;

  // Stage the batch's 2048 points into LDS (xyz + pad).
  #pragma unroll
  for (int r = 0; r < 2; ++r) {
    int p = tid + r * BLOCK;
    float x = base[p * 3 + 0];
    float y = base[p * 3 + 1];
    float z = base[p * 3 + 2];
    pts[p] = make_float4(x, y, z, 0.f);
  }
  __syncthreads();

  const int wave = tid >> 6;
  const int lane = tid & 63;
  const int i = g * WAVES_PER_BLOCK + wave;  // point index within batch
  const float4 pi = pts[i];

  // 32 candidate distances per lane, in registers.
  float d[32];
  float lmin = INFINITY;
  #pragma unroll
  for (int m = 0; m < 32; ++m) {
    float4 c = pts[lane + (m << 6)];
    float dx = pi.x - c.x;
    float dy = pi.y - c.y;
    float dz = pi.z - c.z;
    float dd = fmaf(dz, dz, fmaf(dy, dy, dx * dx));
    d[m] = dd;
    lmin = fminf(lmin, dd);
  }

  // t = 16th smallest lane-min >= true 16th smallest distance.
  float sorted = bitonic64_asc(lmin, lane);
  const float thr = __shfl(sorted, 15);

  // Count qualifying values and wave prefix-sum for compaction offsets.
  int c = 0;
  #pragma unroll
  for (int m = 0; m < 32; ++m) c += (d[m] <= thr) ? 1 : 0;
  int incl = c;
  #pragma unroll
  for (int ofs = 1; ofs < 64; ofs <<= 1) {
    int y = __shfl_up(incl, ofs);
    if (lane >= ofs) incl += y;
  }
  const int mtot = __shfl(incl, 63);
  int idx = incl - c;

  #pragma unroll
  for (int m = 0; m < 32; ++m) {
    bool q = d[m] <= thr;
    if (q) {
      if (idx < 64) scratch[wave][idx] = d[m];
      idx++;
    }
  }
  __syncthreads();  // all waves reach this (orders scratch writes before reads)

  float sum16;
  if (mtot <= 64) {
    float v = (lane < mtot) ? scratch[wave][lane] : INFINITY;
    v = bitonic64_asc(v, lane);
    float contrib = (lane < KSEL) ? v : 0.f;
    #pragma unroll
    for (int ofs = 32; ofs >= 1; ofs >>= 1) contrib += __shfl_xor(contrib, ofs);
    sum16 = contrib;
  } else {
    // Exact fallback: 16 extraction rounds over register-held distances.
    unsigned consumed = 0;
    float s = 0.f;
    for (int r = 0; r < KSEL; ++r) {
      float bv = INFINITY;
      int bi = 0;
      #pragma unroll
      for (int m = 0; m < 32; ++m) {
        bool ok = (((consumed >> m) & 1u) == 0u) && (d[m] < bv);
        bv = ok ? d[m] : bv;
        bi = ok ? m : bi;
      }
      int bl = lane;
      #pragma unroll
      for (int ofs = 32; ofs >= 1; ofs >>= 1) {
        float ov = __shfl_xor(bv, ofs);
        int ol = __shfl_xor(bl, ofs);
        bool take = (ov < bv) || (ov == bv && ol < bl);
        bv = take ? ov : bv;
        bl = take ? ol : bl;
      }
      s += bv;
      if (lane == bl) consumed |= (1u << bi);
    }
    sum16 = s;
  }

  if (lane == 0) out_sums[bid * WAVES_PER_BLOCK + wave] = sum16;
}

__global__ __launch_bounds__(1024) void final_reduce_kernel(
    const float* __restrict__ sums, float* __restrict__ out) {
  __shared__ float partial[16];
  const int tid = threadIdx.x;
  const int wave = tid >> 6;
  const int lane = tid & 63;
  // wave w reduces segment (t,b) = w: 2048 per-point sum16 values.
  float s = 0.f;
  #pragma unroll
  for (int m = 0; m < 32; ++m) s += sums[wave * 2048 + lane + (m << 6)];
  #pragma unroll
  for (int ofs = 32; ofs >= 1; ofs >>= 1) s += __shfl_xor(s, ofs);
  if (lane == 0) partial[wave] = s;
  __syncthreads();
  if (tid == 0) {
    const float scale = 1.f / (2048.f * 16.f);  // mean over points, mean over k
    float acc = 0.f;
    #pragma unroll
    for (int bb = 0; bb < 8; ++bb) {
      float diff = (partial[bb] - partial[8 + bb]) * scale;
      acc += diff * diff;
    }
    out[0] = acc * 0.125f;
  }
}

extern "C" void kernel_launch(void* const* d_in, const int* in_sizes, int n_in,
                              void* d_out, int out_size, void* d_ws, size_t ws_size,
                              hipStream_t stream) {
  const float* seed = (const float*)d_in[0];
  const float* gt = (const float*)d_in[1];
  float* out = (float*)d_out;
  float* ws = (float*)d_ws;  // 32768 floats = 128 KB

  knn_sum16_kernel<<<2048, BLOCK, 0, stream>>>(seed, gt, ws);
  final_reduce_kernel<<<1, 1024, 0, stream>>>(ws, out);
}